// Round 1
// baseline (1074.560 us; speedup 1.0000x reference)
//
#include <hip/hip_runtime.h>
#include <hip/hip_bf16.h>
#include <stdint.h>

// D-MPNN (chemprop MPNEncoder) forward. fp32 in/out; bf16 intermediates, MFMA GEMMs.
// Intermediates use a 320-col padded layout (cols 300..319 == 0): rows 16B-aligned,
// N-tiles divide evenly (320 = 20*16).
// Fused-K identity: relu(inp + m@W_h) = relu([m | f_bonds] @ [[W_h];[W_i]]), K=480.
// R5 changes vs R4 (which was gather-latency bound: MfmaUtil 13.9% == exact MFMA floor,
// HBM 22.5%, stall = random b2a/b2revb row gathers serialized with compute):
//  - raw-hold A prefetch: gathered uint4s kept unconverted in regs; bf16 convert +
//    ds_write happen AFTER the MFMA block (vmcnt wait moves past compute)
//  - depth-2 A pipeline: A(kt+2) issued AFTER B(kt+1) so the bottom-of-loop waits
//    (A(kt+1): vmcnt~7, B(kt+1): vmcnt~2) leave A(kt+2) in flight across the barrier
//  - raw s_barrier + explicit lgkmcnt(0) (no __syncthreads vmcnt(0) drain in main loop)
//  - branchless: gm clamped (C-store guards rows), fp32 k clamped (pad cols hit zero
//    weight rows), tail iterations re-issue last tile (L1 hits)

#define H_DIM 300
#define HP 320
#define AF_DIM 133
#define BF_DIM 147
#define MAXNB 6

typedef __hip_bfloat16 bf16;
typedef __attribute__((ext_vector_type(8))) short short8;
typedef __attribute__((ext_vector_type(4))) float f32x4;

__device__ __forceinline__ float b2f_raw(unsigned short u) {
    union { unsigned int i; float f; } v; v.i = ((unsigned int)u) << 16; return v.f;
}
__device__ __forceinline__ unsigned short f2b_raw(float f) {
    union { float f; unsigned int i; } v; v.f = f;
    unsigned int x = v.i;
    x += 0x7fffu + ((x >> 16) & 1u);   // RNE
    return (unsigned short)(x >> 16);
}

// ---------------------------------------------------------------------------
// Weight prep: Wt[n][k] (bf16, k-contiguous, n<320, k<nkt*32)
//   k < 320 : s1[k*300 + n]      (k < r1, n < 300)
//   k >= 320: s2[(k-320)*300 + n] (k-320 < r2, n < 300)
// ---------------------------------------------------------------------------
__global__ __launch_bounds__(256) void prep_wt(
    const float* __restrict__ s1, int r1,
    const float* __restrict__ s2, int r2,
    unsigned short* __restrict__ Wt, int nkt)
{
    const int Ktot = nkt * 32;
    const int idx = blockIdx.x * 256 + threadIdx.x;
    if (idx >= 320 * Ktot) return;
    const int n = idx % 320;
    const int k = idx / 320;
    float v = 0.f;
    if (n < H_DIM) {
        if (k < 320) { if (k < r1) v = s1[k * H_DIM + n]; }
        else { const int kk = k - 320; if (kk < r2) v = s2[kk * H_DIM + n]; }
    }
    Wt[n * Ktot + k] = f2b_raw(v);
}

// ---------------------------------------------------------------------------
// MFMA GEMM: out[M][320] = relu(A @ W (+bias)). Block: 256 thr, tile 64x320,
// BK=32. Wave w: cols [80w, 80w+80).
// MODE 1: A[k<147] = f_bonds fp32 (stride 147);                     NKT=5
// MODE 2: A[k<300] = amsg[b2a[m]] - msg[b2revb[m]] (bf16, stride 320)
//         A[320<=k<467] = f_bonds fp32 (stride 147);                NKT=15
// MODE 3: A[k<300] = amsg[m] (bf16, stride 320)
//         A[320<=k<453] = f_atoms fp32 (stride 133);                NKT=15
// A LDS chunks XOR-swizzled: chunk c of row r at r*64 + (c^(r&3))*16.
// ---------------------------------------------------------------------------
template <int MODE>
__global__ __launch_bounds__(256) void mfma_gemm(
    const bf16* __restrict__ Ab,    // M2/M3: amsg
    const bf16* __restrict__ Ab2,   // M2: msg_prev
    const float* __restrict__ Afp,  // M1/M2: f_bonds; M3: f_atoms
    const int* __restrict__ idx1,   // M2: b2a
    const int* __restrict__ idx2,   // M2: b2revb
    const unsigned short* __restrict__ Wt,  // [320][NKT*32]
    const float* __restrict__ bias, // M3: b_o
    bf16* __restrict__ out,         // [M][320]
    int M)
{
    constexpr int NKT  = (MODE == 1) ? 5 : 15;
    constexpr int KTOT = NKT * 32;
    constexpr int FPW  = (MODE == 3) ? AF_DIM : BF_DIM;  // fp32 part width

    __shared__ char As[2][64 * 64];   // 2 x 4KB double-buffered A
    __shared__ char Cs[16 * 640];     // 10KB epilogue staging

    const int t    = threadIdx.x;
    const int m0   = blockIdx.x * 64;
    const int wave = t >> 6;
    const int lane = t & 63;
    const int l16  = lane & 15;
    const int quad = lane >> 4;
    const int swz  = ((quad ^ (l16 & 3)) << 4);

    // A-staging mapping: row am (0..63), chunk c (0..3). gm clamped: OOB rows
    // compute garbage, epilogue C-store guards.
    const int am   = t >> 2;
    const int c    = t & 3;
    const int gm   = min(m0 + am, M - 1);
    const int aoff = am * 64 + ((c ^ (am & 3)) << 4);

    int offA = 0, offB = 0;           // 32-bit byte offsets (max 128e6 < 2^31)
    if (MODE == 2) { offA = idx1[gm] * 640; offB = idx2[gm] * 640; }
    if (MODE == 3) { offA = gm * 640; }
    const char* AbC  = (const char*)Ab;
    const char* Ab2C = (const char*)Ab2;

    // Issue global loads for tile kt; raw results held in x/y (no convert here).
    auto issue_a = [&](int kt, uint4& x, uint4& y) {
        if (MODE != 1 && kt < 10) {
            const int koff = kt * 64 + c * 16;
            x = *(const uint4*)(AbC + (unsigned)(offA + koff));
            if (MODE == 2) y = *(const uint4*)(Ab2C + (unsigned)(offB + koff));
        } else {
            const int kb = (MODE == 1 ? kt * 32 : (kt - 10) * 32) + c * 8;
            float* xp = (float*)&x;
            float* yp = (float*)&y;
#pragma unroll
            for (int j = 0; j < 8; ++j) {
                // clamp instead of mask: k >= FPW columns hit zeroed weight rows
                const int kk = min(kb + j, FPW - 1);
                const float v = Afp[gm * FPW + kk];
                if (j < 4) xp[j] = v; else yp[j - 4] = v;
            }
        }
    };
    // Convert raw-held tile kt to bf16x8 (forces the vmcnt wait at this point).
    auto conv_a = [&](int kt, const uint4& x, const uint4& y) -> uint4 {
        uint4 r;
        unsigned short* rp = (unsigned short*)&r;
        if (MODE == 1 || kt >= 10) {
            const float* xp = (const float*)&x;
            const float* yp = (const float*)&y;
#pragma unroll
            for (int j = 0; j < 8; ++j) rp[j] = f2b_raw(j < 4 ? xp[j] : yp[j - 4]);
        } else if (MODE == 2) {
            const unsigned short* ap = (const unsigned short*)&x;
            const unsigned short* bp = (const unsigned short*)&y;
#pragma unroll
            for (int j = 0; j < 8; ++j)
                rp[j] = f2b_raw(b2f_raw(ap[j]) - b2f_raw(bp[j]));
        } else {
            r = x;                     // MODE 3, kt<10: already bf16
        }
        return r;
    };

    auto load_b = [&](int kt, short8* bfr) {
        const int kbase = kt * 32 + quad * 8;
#pragma unroll
        for (int nt = 0; nt < 5; ++nt) {
            const int nn = wave * 80 + nt * 16 + l16;
            bfr[nt] = *(const short8*)(Wt + (long)nn * KTOT + kbase);
        }
    };

    f32x4 acc[4][5];
#pragma unroll
    for (int i = 0; i < 4; ++i)
#pragma unroll
        for (int j = 0; j < 5; ++j) acc[i][j] = (f32x4){0.f, 0.f, 0.f, 0.f};

    // prologue: tile0 -> LDS (full wait, once); then B(0), then A(1) in flight.
    // FIFO order matters: B(0) issued BEFORE A(1) so waiting on B(0) at the first
    // MFMA block does not drain A(1).
    uint4 x0, y0, x1, y1;
    issue_a(0, x0, y0);
    *(uint4*)(As[0] + aoff) = conv_a(0, x0, y0);
    short8 bfr[5], bfr_n[5];
    load_b(0, bfr);
    issue_a(1, x0, y0);

    for (int kt = 0; kt < NKT; ++kt) {
        const int ktn  = (kt + 1 < NKT) ? kt + 1 : NKT - 1;   // tail: re-issue last tile
        const int ktn2 = (kt + 2 < NKT) ? kt + 2 : NKT - 1;
        load_b(ktn, bfr_n);           // B(kt+1): 5 loads (L2-resident)
        issue_a(ktn2, x1, y1);        // A(kt+2): gathers stay in flight past this iter
        asm volatile("s_waitcnt lgkmcnt(0)" ::: "memory");    // drain own ds ops
        __builtin_amdgcn_s_barrier();                          // no vmcnt drain
#pragma unroll
        for (int mt = 0; mt < 4; ++mt) {
            const short8 afr = *(const short8*)(As[kt & 1] + mt * 1024 + l16 * 64 + swz);
#pragma unroll
            for (int nt = 0; nt < 5; ++nt)
                acc[mt][nt] = __builtin_amdgcn_mfma_f32_16x16x32_bf16(
                    afr, bfr[nt], acc[mt][nt], 0, 0, 0);
        }
        __builtin_amdgcn_sched_barrier(0);   // keep the vmcnt wait below the MFMAs
        // waits A(kt+1) (vmcnt leaves B(kt+1)+A(kt+2) outstanding), then writes LDS.
        // Buffer (kt+1)&1 was last read in iter kt-1; barrier above made that safe.
        *(uint4*)(As[(kt + 1) & 1] + aoff) = conv_a(ktn, x0, y0);
        x0 = x1; y0 = y1;
#pragma unroll
        for (int nt = 0; nt < 5; ++nt) bfr[nt] = bfr_n[nt];   // waits B(kt+1) only
    }

    // epilogue: per 16-row strip, LDS transpose -> coalesced 16B stores
    for (int mt = 0; mt < 4; ++mt) {
        __syncthreads();
#pragma unroll
        for (int nt = 0; nt < 5; ++nt) {
            const int col = wave * 80 + nt * 16 + l16;
            float bv = 0.f;
            if (MODE == 3) bv = (col < H_DIM) ? bias[col] : 0.f;
#pragma unroll
            for (int r = 0; r < 4; ++r) {
                const float v = fmaxf(acc[mt][nt][r] + bv, 0.f);
                ((unsigned short*)Cs)[(quad * 4 + r) * HP + col] = f2b_raw(v);
            }
        }
        __syncthreads();
        const int gr0 = m0 + mt * 16;
#pragma unroll
        for (int i = 0; i < 3; ++i) {       // 640 16B-chunks, 256 threads
            const int idx = i * 256 + t;
            if (idx < 640) {
                const int row = idx / 40;   // 40 chunks per 640B row
                if (gr0 + row < M)
                    *(uint4*)((char*)out + (long)(gr0 + row) * 640 + (idx - row * 40) * 16)
                        = *(const uint4*)(Cs + idx * 16);
            }
        }
    }
}

// amsg[a][0:320] = sum_{j<6} msg[a2b[a][j]][0:320]; thread = (atom, 8-col chunk)
__global__ __launch_bounds__(256) void gather_sum_kernel(
    const bf16* __restrict__ msg, const int* __restrict__ a2b,
    bf16* __restrict__ amsg, int n_atoms)
{
    const int idx = blockIdx.x * 256 + threadIdx.x;
    if (idx >= n_atoms * (HP / 8)) return;
    const int a = idx / (HP / 8);
    const int cc = idx - a * (HP / 8);
    float s[8] = {0.f, 0.f, 0.f, 0.f, 0.f, 0.f, 0.f, 0.f};
    const int base = a * MAXNB;
#pragma unroll
    for (int j = 0; j < MAXNB; ++j) {
        const long b = a2b[base + j];
        const uint4 u = *(const uint4*)((const char*)msg + (b * HP + cc * 8) * 2);
        const unsigned short* up = (const unsigned short*)&u;
#pragma unroll
        for (int e = 0; e < 8; ++e) s[e] += b2f_raw(up[e]);
    }
    uint4 r;
    unsigned short* rp = (unsigned short*)&r;
#pragma unroll
    for (int e = 0; e < 8; ++e) rp[e] = f2b_raw(s[e]);
    *(uint4*)((char*)amsg + ((long)a * HP + cc * 8) * 2) = r;
}

// Per-molecule mean; atom_mol sorted ascending -> binary search range, no atomics.
__global__ __launch_bounds__(256) void seg_mean_kernel(
    const bf16* __restrict__ hidden, const int* __restrict__ atom_mol,
    float* __restrict__ out, int n_atoms)
{
    const int m = blockIdx.x;
    __shared__ int s_lo, s_hi;
    if (threadIdx.x == 0) {
        int lo = 0, hi = n_atoms;
        while (lo < hi) { int mid = (lo + hi) >> 1; if (atom_mol[mid] < m) lo = mid + 1; else hi = mid; }
        s_lo = lo;
        int lo2 = lo; hi = n_atoms;
        while (lo2 < hi) { int mid = (lo2 + hi) >> 1; if (atom_mol[mid] < m + 1) lo2 = mid + 1; else hi = mid; }
        s_hi = lo2;
    }
    __syncthreads();
    const int lo = s_lo, hi = s_hi;
    const float inv = 1.0f / (float)max(hi - lo, 1);
    for (int cpass = 0; cpass < 2; ++cpass) {
        const int c = cpass * 256 + threadIdx.x;
        if (c >= H_DIM) break;
        float s = 0.f;
        for (int a = lo; a < hi; ++a)
            s += b2f_raw(((const unsigned short*)hidden)[(long)a * HP + c]);
        out[(long)m * H_DIM + c] = s * inv;
    }
}

extern "C" void kernel_launch(void* const* d_in, const int* in_sizes, int n_in,
                              void* d_out, int out_size, void* d_ws, size_t ws_size,
                              hipStream_t stream)
{
    const float* f_atoms = (const float*)d_in[0];
    const float* f_bonds = (const float*)d_in[1];
    const float* W_i     = (const float*)d_in[2];
    const float* W_h     = (const float*)d_in[3];
    const float* W_o     = (const float*)d_in[4];
    const float* b_o     = (const float*)d_in[5];
    const int*  a2b      = (const int*)d_in[6];
    const int*  b2a      = (const int*)d_in[7];
    const int*  b2revb   = (const int*)d_in[8];
    const int*  atom_mol = (const int*)d_in[9];

    const int n_atoms = in_sizes[0] / AF_DIM;   // 100000
    const int n_bonds = in_sizes[1] / BF_DIM;   // 200000
    const int n_mols  = out_size / H_DIM;       // 4000

    char* ws = (char*)d_ws;
    size_t off = 0;
    auto alloc = [&](size_t bytes) {
        size_t o = off; off += (bytes + 255) & ~(size_t)255; return o;
    };
    bf16* msgA = (bf16*)(ws + alloc((size_t)n_bonds * HP * 2));   // 128 MB
    bf16* msgB = (bf16*)(ws + alloc((size_t)n_bonds * HP * 2));   // 128 MB
    bf16* amsg = (bf16*)(ws + alloc((size_t)n_atoms * HP * 2));   //  64 MB
    unsigned short* Wt1 = (unsigned short*)(ws + alloc(320 * 160 * 2));
    unsigned short* Wt2 = (unsigned short*)(ws + alloc(320 * 480 * 2));
    unsigned short* Wt3 = (unsigned short*)(ws + alloc(320 * 480 * 2));
    bf16* hidden = msgB;  // msgB dead after 2nd depth GEMM

    const dim3 blk(256);

    // weight prep (Wt3: amsg part = W_o rows 133.., atom part = W_o rows 0..132)
    prep_wt<<<(320 * 160 + 255) / 256, blk, 0, stream>>>(W_i, BF_DIM, nullptr, 0, Wt1, 5);
    prep_wt<<<(320 * 480 + 255) / 256, blk, 0, stream>>>(W_h, H_DIM, W_i, BF_DIM, Wt2, 15);
    prep_wt<<<(320 * 480 + 255) / 256, blk, 0, stream>>>(W_o + (size_t)AF_DIM * H_DIM, H_DIM,
                                                         W_o, AF_DIM, Wt3, 15);

    const int gB = (n_bonds + 63) / 64;   // 3125
    const int gA = (n_atoms + 63) / 64;   // 1563
    const int gG = (n_atoms * (HP / 8) + 255) / 256;

    // msg0 = relu(f_bonds @ W_i)
    mfma_gemm<1><<<gB, blk, 0, stream>>>(nullptr, nullptr, f_bonds, nullptr, nullptr,
                                         Wt1, nullptr, msgA, n_bonds);
    // depth 1: msgA -> msgB
    gather_sum_kernel<<<gG, blk, 0, stream>>>(msgA, a2b, amsg, n_atoms);
    mfma_gemm<2><<<gB, blk, 0, stream>>>(amsg, msgA, f_bonds, b2a, b2revb,
                                         Wt2, nullptr, msgB, n_bonds);
    // depth 2: msgB -> msgA
    gather_sum_kernel<<<gG, blk, 0, stream>>>(msgB, a2b, amsg, n_atoms);
    mfma_gemm<2><<<gB, blk, 0, stream>>>(amsg, msgB, f_bonds, b2a, b2revb,
                                         Wt2, nullptr, msgA, n_bonds);
    // final aggregation + readout
    gather_sum_kernel<<<gG, blk, 0, stream>>>(msgA, a2b, amsg, n_atoms);
    mfma_gemm<3><<<gA, blk, 0, stream>>>(amsg, nullptr, f_atoms, nullptr, nullptr,
                                         Wt3, b_o, hidden, n_atoms);
    // per-molecule mean
    seg_mean_kernel<<<n_mols, blk, 0, stream>>>(hidden, atom_mol, (float*)d_out, n_atoms);
}

// Round 2
// 960.558 us; speedup vs baseline: 1.1187x; 1.1187x over previous
//
#include <hip/hip_runtime.h>
#include <hip/hip_bf16.h>
#include <stdint.h>

// D-MPNN (chemprop MPNEncoder) forward. fp32 in/out; bf16 intermediates, MFMA GEMMs.
// Intermediates use a 320-col padded layout (cols 300..319 == 0).
// R6: algebraic restructure. Row-gather commutes with GEMM:
//   (amsg[b2a] - msg[b2revb]) @ W_h = Gh[b2a] - Hm[b2revb],
//   Hm = msg @ W_h,  Gh = gather_sum(Hm)   (linearity through the neighbor sum).
// So each layer = streaming GEMM (contiguous A, K=320) + gather_sum + elementwise
// combine kernel. No gathers inside any GEMM. GEMM inner loop reverted to the
// proven R4 structure (R5's hand-pipelined variant regressed 179->247 us).
// inp = f_bonds @ W_i stored raw once; relu folded into layer-1 A-load (bf16 sign
// mask), so msg0 is never materialized.

#define H_DIM 300
#define HP 320
#define AF_DIM 133
#define BF_DIM 147
#define MAXNB 6

typedef __hip_bfloat16 bf16;
typedef __attribute__((ext_vector_type(8))) short short8;
typedef __attribute__((ext_vector_type(4))) float f32x4;

__device__ __forceinline__ float b2f_raw(unsigned short u) {
    union { unsigned int i; float f; } v; v.i = ((unsigned int)u) << 16; return v.f;
}
__device__ __forceinline__ unsigned short f2b_raw(float f) {
    union { float f; unsigned int i; } v; v.f = f;
    unsigned int x = v.i;
    x += 0x7fffu + ((x >> 16) & 1u);   // RNE
    return (unsigned short)(x >> 16);
}

// ---------------------------------------------------------------------------
// Weight prep: Wt[n][k] (bf16, k-contiguous, n<320, k<nkt*32)
//   k < 320 : s1[k*300 + n]      (k < r1, n < 300)
//   k >= 320: s2[(k-320)*300 + n] (k-320 < r2, n < 300)
// ---------------------------------------------------------------------------
__global__ __launch_bounds__(256) void prep_wt(
    const float* __restrict__ s1, int r1,
    const float* __restrict__ s2, int r2,
    unsigned short* __restrict__ Wt, int nkt)
{
    const int Ktot = nkt * 32;
    const int idx = blockIdx.x * 256 + threadIdx.x;
    if (idx >= 320 * Ktot) return;
    const int n = idx % 320;
    const int k = idx / 320;
    float v = 0.f;
    if (n < H_DIM) {
        if (k < 320) { if (k < r1) v = s1[k * H_DIM + n]; }
        else { const int kk = k - 320; if (kk < r2) v = s2[kk * H_DIM + n]; }
    }
    Wt[n * Ktot + k] = f2b_raw(v);
}

// ---------------------------------------------------------------------------
// MFMA GEMM: out[M][320] = act(A @ W (+bias)). Block: 256 thr, tile 64x320,
// BK=32. Wave w: cols [80w, 80w+80).
// MODE 1: A[k<147] = f_bonds fp32 (stride 147);          NKT=5,  raw out (inp)
// MODE 4: A[k<300] = Ab bf16 contiguous (stride 320);    NKT=10, raw out (Hm)
//         RELU_A: apply relu to A on load (bf16 sign mask)
// MODE 3: A[k<300] = amsg bf16; A[320<=k<453] = f_atoms fp32; NKT=15,
//         bias + relu out (readout)
// A LDS chunks XOR-swizzled: chunk c of row r at r*64 + (c^(r&3))*16.
// ---------------------------------------------------------------------------
template <int MODE, bool RELU_A>
__global__ __launch_bounds__(256) void mfma_gemm(
    const bf16* __restrict__ Ab,    // M4: msg/inp; M3: amsg
    const float* __restrict__ Afp,  // M1: f_bonds; M3: f_atoms
    const unsigned short* __restrict__ Wt,  // [320][NKT*32]
    const float* __restrict__ bias, // M3: b_o
    bf16* __restrict__ out,         // [M][320]
    int M)
{
    constexpr int NKT  = (MODE == 1) ? 5 : (MODE == 4 ? 10 : 15);
    constexpr int KTOT = NKT * 32;
    constexpr int FPW  = (MODE == 3) ? AF_DIM : BF_DIM;  // fp32 part width
    constexpr bool RELU_OUT = (MODE == 3);

    __shared__ char As[2][64 * 64];   // 2 x 4KB double-buffered A
    __shared__ char Cs[16 * 640];     // 10KB epilogue staging

    const int t    = threadIdx.x;
    const int m0   = blockIdx.x * 64;
    const int wave = t >> 6;
    const int lane = t & 63;
    const int l16  = lane & 15;
    const int quad = lane >> 4;
    const int swz  = ((quad ^ (l16 & 3)) << 4);

    // A-staging mapping: row am (0..63), chunk c (0..3)
    const int am  = t >> 2;
    const int c   = t & 3;
    const int gm  = m0 + am;
    const bool mok = (gm < M);
    const int aoff = am * 64 + ((c ^ (am & 3)) << 4);

    auto load_a = [&](int kt) -> uint4 {
        uint4 aval = {0u, 0u, 0u, 0u};
        if (!mok) return aval;
        if (MODE == 1) {
            const int k = kt * 32 + c * 8;
            unsigned short* rp = (unsigned short*)&aval;
#pragma unroll
            for (int j = 0; j < 8; ++j) {
                const int kk = k + j;
                rp[j] = (kk < BF_DIM) ? f2b_raw(Afp[(long)gm * BF_DIM + kk]) : 0;
            }
        } else if (MODE == 4 || kt < 10) {
            const int k = kt * 32 + c * 8;
            aval = *(const uint4*)((const char*)Ab + ((long)gm * HP + k) * 2);
            if (RELU_A) {               // relu on bf16: clear negative lanes
                unsigned short* rp = (unsigned short*)&aval;
#pragma unroll
                for (int j = 0; j < 8; ++j)
                    rp[j] = (rp[j] & 0x8000u) ? 0 : rp[j];
            }
        } else {                        // MODE 3 fp32 tail (f_atoms)
            const int k2 = (kt - 10) * 32 + c * 8;
            unsigned short* rp = (unsigned short*)&aval;
#pragma unroll
            for (int j = 0; j < 8; ++j) {
                const int kk = k2 + j;
                rp[j] = (kk < FPW) ? f2b_raw(Afp[(long)gm * FPW + kk]) : 0;
            }
        }
        return aval;
    };

    auto load_b = [&](int kt, short8* bfr) {
        const int kbase = kt * 32 + quad * 8;
#pragma unroll
        for (int nt = 0; nt < 5; ++nt) {
            const int nn = wave * 80 + nt * 16 + l16;
            bfr[nt] = *(const short8*)(Wt + (long)nn * KTOT + kbase);
        }
    };

    f32x4 acc[4][5];
#pragma unroll
    for (int i = 0; i < 4; ++i)
#pragma unroll
        for (int j = 0; j < 5; ++j) acc[i][j] = (f32x4){0.f, 0.f, 0.f, 0.f};

    // prologue: stage A(0), fetch B(0)
    uint4 aval = load_a(0);
    *(uint4*)(As[0] + aoff) = aval;
    short8 bfr[5];
    load_b(0, bfr);

    for (int kt = 0; kt < NKT; ++kt) {
        short8 bfr_n[5];
        if (kt + 1 < NKT) {                 // prefetch next iteration (global)
            aval = load_a(kt + 1);
            load_b(kt + 1, bfr_n);
        }
        __syncthreads();                    // As[kt&1] visible to all waves
        short8 afr[4];
#pragma unroll
        for (int mt = 0; mt < 4; ++mt)
            afr[mt] = *(const short8*)(As[kt & 1] + mt * 1024 + l16 * 64 + swz);
#pragma unroll
        for (int nt = 0; nt < 5; ++nt)
#pragma unroll
            for (int mt = 0; mt < 4; ++mt)
                acc[mt][nt] = __builtin_amdgcn_mfma_f32_16x16x32_bf16(
                    afr[mt], bfr[nt], acc[mt][nt], 0, 0, 0);
        if (kt + 1 < NKT) {
            *(uint4*)(As[(kt + 1) & 1] + aoff) = aval;  // safe: buffer last read in kt-1
#pragma unroll
            for (int nt = 0; nt < 5; ++nt) bfr[nt] = bfr_n[nt];
        }
    }

    // epilogue: per 16-row strip, LDS transpose -> coalesced 16B stores
    for (int mt = 0; mt < 4; ++mt) {
        __syncthreads();
#pragma unroll
        for (int nt = 0; nt < 5; ++nt) {
            const int col = wave * 80 + nt * 16 + l16;
            float bv = 0.f;
            if (MODE == 3) bv = (col < H_DIM) ? bias[col] : 0.f;
#pragma unroll
            for (int r = 0; r < 4; ++r) {
                float v = acc[mt][nt][r] + bv;
                if (RELU_OUT) v = fmaxf(v, 0.f);
                ((unsigned short*)Cs)[(quad * 4 + r) * HP + col] = f2b_raw(v);
            }
        }
        __syncthreads();
        const int gr0 = m0 + mt * 16;
#pragma unroll
        for (int i = 0; i < 3; ++i) {       // 640 16B-chunks, 256 threads
            const int idx = i * 256 + t;
            if (idx < 640) {
                const int row = idx / 40;   // 40 chunks per 640B row
                if (gr0 + row < M)
                    *(uint4*)((char*)out + (long)(gr0 + row) * 640 + (idx - row * 40) * 16)
                        = *(const uint4*)(Cs + idx * 16);
            }
        }
    }
}

// amsg[a][0:320] = sum_{j<6} msg[a2b[a][j]][0:320]; thread = (atom, 8-col chunk)
__global__ __launch_bounds__(256) void gather_sum_kernel(
    const bf16* __restrict__ msg, const int* __restrict__ a2b,
    bf16* __restrict__ amsg, int n_atoms)
{
    const int idx = blockIdx.x * 256 + threadIdx.x;
    if (idx >= n_atoms * (HP / 8)) return;
    const int a = idx / (HP / 8);
    const int cc = idx - a * (HP / 8);
    float s[8] = {0.f, 0.f, 0.f, 0.f, 0.f, 0.f, 0.f, 0.f};
    const int base = a * MAXNB;
#pragma unroll
    for (int j = 0; j < MAXNB; ++j) {
        const long b = a2b[base + j];
        const uint4 u = *(const uint4*)((const char*)msg + (b * HP + cc * 8) * 2);
        const unsigned short* up = (const unsigned short*)&u;
#pragma unroll
        for (int e = 0; e < 8; ++e) s[e] += b2f_raw(up[e]);
    }
    uint4 r;
    unsigned short* rp = (unsigned short*)&r;
#pragma unroll
    for (int e = 0; e < 8; ++e) rp[e] = f2b_raw(s[e]);
    *(uint4*)((char*)amsg + ((long)a * HP + cc * 8) * 2) = r;
}

// msg'[b] = relu(inp[b] + Gh[b2a[b]] - Hm[b2revb[b]]); thread = (bond, 8-col chunk)
__global__ __launch_bounds__(256) void combine_kernel(
    const bf16* __restrict__ inp, const bf16* __restrict__ Gh,
    const bf16* __restrict__ Hm, const int* __restrict__ b2a,
    const int* __restrict__ b2revb, bf16* __restrict__ outm, int n_bonds)
{
    const int idx = blockIdx.x * 256 + threadIdx.x;
    if (idx >= n_bonds * (HP / 8)) return;
    const int b = idx / (HP / 8);
    const int cc = idx - b * (HP / 8);
    const long co = (long)cc * 16;
    const long ra = b2a[b];
    const long rb = b2revb[b];
    const uint4 vi = *(const uint4*)((const char*)inp + (long)b * 640 + co);
    const uint4 vg = *(const uint4*)((const char*)Gh + ra * 640 + co);
    const uint4 vh = *(const uint4*)((const char*)Hm + rb * 640 + co);
    const unsigned short* ip = (const unsigned short*)&vi;
    const unsigned short* gp = (const unsigned short*)&vg;
    const unsigned short* hp = (const unsigned short*)&vh;
    uint4 r;
    unsigned short* rp = (unsigned short*)&r;
#pragma unroll
    for (int e = 0; e < 8; ++e) {
        const float v = b2f_raw(ip[e]) + b2f_raw(gp[e]) - b2f_raw(hp[e]);
        rp[e] = f2b_raw(fmaxf(v, 0.f));
    }
    *(uint4*)((char*)outm + (long)b * 640 + co) = r;
}

// Per-molecule mean; atom_mol sorted ascending -> binary search range, no atomics.
__global__ __launch_bounds__(256) void seg_mean_kernel(
    const bf16* __restrict__ hidden, const int* __restrict__ atom_mol,
    float* __restrict__ out, int n_atoms)
{
    const int m = blockIdx.x;
    __shared__ int s_lo, s_hi;
    if (threadIdx.x == 0) {
        int lo = 0, hi = n_atoms;
        while (lo < hi) { int mid = (lo + hi) >> 1; if (atom_mol[mid] < m) lo = mid + 1; else hi = mid; }
        s_lo = lo;
        int lo2 = lo; hi = n_atoms;
        while (lo2 < hi) { int mid = (lo2 + hi) >> 1; if (atom_mol[mid] < m + 1) lo2 = mid + 1; else hi = mid; }
        s_hi = lo2;
    }
    __syncthreads();
    const int lo = s_lo, hi = s_hi;
    const float inv = 1.0f / (float)max(hi - lo, 1);
    for (int cpass = 0; cpass < 2; ++cpass) {
        const int c = cpass * 256 + threadIdx.x;
        if (c >= H_DIM) break;
        float s = 0.f;
        for (int a = lo; a < hi; ++a)
            s += b2f_raw(((const unsigned short*)hidden)[(long)a * HP + c]);
        out[(long)m * H_DIM + c] = s * inv;
    }
}

extern "C" void kernel_launch(void* const* d_in, const int* in_sizes, int n_in,
                              void* d_out, int out_size, void* d_ws, size_t ws_size,
                              hipStream_t stream)
{
    const float* f_atoms = (const float*)d_in[0];
    const float* f_bonds = (const float*)d_in[1];
    const float* W_i     = (const float*)d_in[2];
    const float* W_h     = (const float*)d_in[3];
    const float* W_o     = (const float*)d_in[4];
    const float* b_o     = (const float*)d_in[5];
    const int*  a2b      = (const int*)d_in[6];
    const int*  b2a      = (const int*)d_in[7];
    const int*  b2revb   = (const int*)d_in[8];
    const int*  atom_mol = (const int*)d_in[9];

    const int n_atoms = in_sizes[0] / AF_DIM;   // 100000
    const int n_bonds = in_sizes[1] / BF_DIM;   // 200000
    const int n_mols  = out_size / H_DIM;       // 4000

    char* ws = (char*)d_ws;
    size_t off = 0;
    auto alloc = [&](size_t bytes) {
        size_t o = off; off += (bytes + 255) & ~(size_t)255; return o;
    };
    bf16* inpB = (bf16*)(ws + alloc((size_t)n_bonds * HP * 2));   // 128 MB (raw inp)
    bf16* msgX = (bf16*)(ws + alloc((size_t)n_bonds * HP * 2));   // 128 MB (msg1/msg2)
    bf16* HmB  = (bf16*)(ws + alloc((size_t)n_bonds * HP * 2));   // 128 MB (Hm per layer)
    bf16* amsg = (bf16*)(ws + alloc((size_t)n_atoms * HP * 2));   //  64 MB (Gh / amsg)
    unsigned short* Wt1 = (unsigned short*)(ws + alloc(320 * 160 * 2));
    unsigned short* WtH = (unsigned short*)(ws + alloc(320 * 320 * 2));
    unsigned short* Wt3 = (unsigned short*)(ws + alloc(320 * 480 * 2));
    bf16* hidden = HmB;  // HmB dead after combine-2

    const dim3 blk(256);

    // weight prep (Wt3: amsg part = W_o rows 133.., atom part = W_o rows 0..132)
    prep_wt<<<(320 * 160 + 255) / 256, blk, 0, stream>>>(W_i, BF_DIM, nullptr, 0, Wt1, 5);
    prep_wt<<<(320 * 320 + 255) / 256, blk, 0, stream>>>(W_h, H_DIM, nullptr, 0, WtH, 10);
    prep_wt<<<(320 * 480 + 255) / 256, blk, 0, stream>>>(W_o + (size_t)AF_DIM * H_DIM, H_DIM,
                                                         W_o, AF_DIM, Wt3, 15);

    const int gB = (n_bonds + 63) / 64;   // 3125
    const int gA = (n_atoms + 63) / 64;   // 1563
    const int gG = (n_atoms * (HP / 8) + 255) / 256;
    const int gC = (n_bonds * (HP / 8) + 255) / 256;

    // inp = f_bonds @ W_i (raw, no relu; msg0 = relu(inp) folded into layer-1 A-load)
    mfma_gemm<1, false><<<gB, blk, 0, stream>>>(nullptr, f_bonds, Wt1, nullptr, inpB, n_bonds);

    // layer 1: Hm = relu(inp) @ W_h; Gh = gsum(Hm); msg1 = relu(inp + Gh[b2a] - Hm[b2revb])
    mfma_gemm<4, true><<<gB, blk, 0, stream>>>(inpB, nullptr, WtH, nullptr, HmB, n_bonds);
    gather_sum_kernel<<<gG, blk, 0, stream>>>(HmB, a2b, amsg, n_atoms);
    combine_kernel<<<gC, blk, 0, stream>>>(inpB, amsg, HmB, b2a, b2revb, msgX, n_bonds);

    // layer 2: Hm = msg1 @ W_h; Gh = gsum(Hm); msg2 = relu(inp + Gh[b2a] - Hm[b2revb])
    mfma_gemm<4, false><<<gB, blk, 0, stream>>>(msgX, nullptr, WtH, nullptr, HmB, n_bonds);
    gather_sum_kernel<<<gG, blk, 0, stream>>>(HmB, a2b, amsg, n_atoms);
    combine_kernel<<<gC, blk, 0, stream>>>(inpB, amsg, HmB, b2a, b2revb, msgX, n_bonds);

    // readout: amsg = gsum(msg2); hidden = relu([amsg | f_atoms] @ W_o + b_o)
    gather_sum_kernel<<<gG, blk, 0, stream>>>(msgX, a2b, amsg, n_atoms);
    mfma_gemm<3, false><<<gA, blk, 0, stream>>>(amsg, f_atoms, Wt3, b_o, hidden, n_atoms);

    // per-molecule mean
    seg_mean_kernel<<<n_mols, blk, 0, stream>>>(hidden, atom_mol, (float*)d_out, n_atoms);
}